// Round 1
// baseline (948.354 us; speedup 1.0000x reference)
//
#include <hip/hip_runtime.h>
#include <stdint.h>

typedef __attribute__((ext_vector_type(8))) short short8;
typedef __attribute__((ext_vector_type(4))) float f32x4;
typedef unsigned short u16;
typedef unsigned int u32;

// ---------------- workspace layout (bytes) ----------------
#define WS_TOK   0ull           // tokens bf16 [32768][256]            16 MB
#define WS_XT    16777216ull    // x_t -> xm_tc -> r1 fp32 [T][C]      32 MB
#define WS_XMCT  50331648ull    // xm fp32 [C][T]                      32 MB
#define WS_GATES 83886080ull    // gates fp32 [T][8]                    1 MB
#define WS_H     84934656ull    // h bf16 [T][256]                     16 MB
#define WS_MOE   101711872ull   // moe acc fp32 [T][256]               32 MB
#define WS_P1    135266304ull   // padded bf16 [34^3][256]             19.2MB
#define WS_P2    155389952ull
#define WS_Y     175513600ull   // conv out fp32 [T][256]              32 MB
#define WS_R2    209068032ull   // r2 bf16 [T][256]                    16 MB
#define WS_WRB   225845248ull   // packed rb conv w bf16 [4][27][256][256]
#define WS_W1P   240001024ull   // w1 packed bf16 [8][256][256]
#define WS_W2P   241049600ull
#define WS_C8P   242098176ull
#define WS_PART  242229248ull   // bn partials [2][256][256] fp32
#define WS_SF    242753536ull   // bn scale/shift [2][256]
#define WS_AUXP  242755584ull   // aux partials [128][16]

__device__ __forceinline__ u16 f2bf(float f) {
  u32 x = __float_as_uint(f);
  u32 r = x + 0x7fffu + ((x >> 16) & 1u);
  return (u16)(r >> 16);
}

__device__ __forceinline__ float gelu_f(float x) {
  float u = 0.7978845608028654f * (x + 0.044715f * x * x * x);
  return 0.5f * x * (1.0f + tanhf(u));
}

// ---------------- transpose x [C][T] -> x_t fp32 + tokens bf16 [T][C] ----------------
__global__ void trans_in_k(const float* __restrict__ x, float* __restrict__ xt,
                           u16* __restrict__ tok) {
  __shared__ float ld[64][65];
  int tt = blockIdx.x, cc = blockIdx.y, tid = threadIdx.x;
#pragma unroll
  for (int k = 0; k < 16; ++k) {
    int idx = tid + k * 256;
    int cl = idx >> 6, j = idx & 63;
    ld[cl][j] = x[(size_t)(cc * 64 + cl) * 32768 + tt * 64 + j];
  }
  __syncthreads();
#pragma unroll
  for (int k = 0; k < 16; ++k) {
    int idx = tid + k * 256;
    int tl = idx >> 6, cl = idx & 63;
    float v = ld[cl][tl];
    size_t o = (size_t)(tt * 64 + tl) * 256 + cc * 64 + cl;
    xt[o] = v;
    tok[o] = f2bf(v);
  }
}

// ---------------- pack resblock conv weights [oc][ic][27] fp32 -> [conv][tap][oc][ic] bf16 ----
__global__ void pack_rb_k(const float* __restrict__ w0, const float* __restrict__ w1,
                          const float* __restrict__ w2, const float* __restrict__ w3,
                          u16* __restrict__ out) {
  __shared__ float ld[6912];
  int conv = blockIdx.x >> 8, blk = blockIdx.x & 255, tid = threadIdx.x;
  const float* src = conv == 0 ? w0 : conv == 1 ? w1 : conv == 2 ? w2 : w3;
  size_t base = (size_t)blk * 256 * 27;
#pragma unroll
  for (int k = 0; k < 27; ++k) ld[tid + k * 256] = src[base + tid + k * 256];
  __syncthreads();
  u16* dst = out + (size_t)conv * 27 * 65536;
  int n = blk * 256 + tid;
#pragma unroll
  for (int tap = 0; tap < 27; ++tap)
    dst[(size_t)tap * 65536 + n] = f2bf(ld[tid * 27 + tap]);
}

// ---------------- transpose-pack w1/w2 256x256 matrices to [N][K] bf16 ----------------
__global__ void pack_tr_k(const float* __restrict__ w1, const float* __restrict__ w2,
                          u16* __restrict__ w1p, u16* __restrict__ w2p) {
  __shared__ float ld[64][65];
  int m = blockIdx.y, tile = blockIdx.x, tid = threadIdx.x;
  const float* src = (m < 8) ? (w1 + (size_t)m * 65536) : (w2 + (size_t)(m - 8) * 65536);
  u16* dst = (m < 8) ? (w1p + (size_t)m * 65536) : (w2p + (size_t)(m - 8) * 65536);
  int r0 = (tile >> 2) * 64, c0 = (tile & 3) * 64;
#pragma unroll
  for (int k = 0; k < 16; ++k) {
    int idx = tid + k * 256;
    int rr = idx >> 6, cc = idx & 63;
    ld[rr][cc] = src[(size_t)(r0 + rr) * 256 + c0 + cc];
  }
  __syncthreads();
#pragma unroll
  for (int k = 0; k < 16; ++k) {
    int idx = tid + k * 256;
    int cc = idx >> 6, rr = idx & 63;
    dst[(size_t)(c0 + cc) * 256 + r0 + rr] = f2bf(ld[rr][cc]);
  }
}

__global__ void cvt_k(const float* __restrict__ in, u16* __restrict__ out, int n) {
  int i = blockIdx.x * 256 + threadIdx.x;
  if (i < n) out[i] = f2bf(in[i]);
}

// ---------------- gating: softmax + top2 + aux partials ----------------
__global__ void gate_k(const float* __restrict__ xt, const float* __restrict__ wg,
                       float* __restrict__ gates, float* __restrict__ auxp) {
  __shared__ float wgs[2048];
  __shared__ float ax[4][16];
  int tid = threadIdx.x;
#pragma unroll
  for (int k = 0; k < 8; ++k) wgs[tid + k * 256] = wg[tid + k * 256];
  __syncthreads();
  int t = blockIdx.x * 256 + tid;
  int lane = tid & 63, wv = tid >> 6;
  float l[8] = {0, 0, 0, 0, 0, 0, 0, 0};
  const float* xr = xt + (size_t)t * 256;
  for (int c = 0; c < 256; c += 4) {
    float4 xv = *(const float4*)(xr + c);
#pragma unroll
    for (int e = 0; e < 8; ++e)
      l[e] += xv.x * wgs[c * 8 + e] + xv.y * wgs[(c + 1) * 8 + e] +
              xv.z * wgs[(c + 2) * 8 + e] + xv.w * wgs[(c + 3) * 8 + e];
  }
  float mx = l[0];
#pragma unroll
  for (int e = 1; e < 8; ++e) mx = fmaxf(mx, l[e]);
  float p[8], sum = 0.f;
#pragma unroll
  for (int e = 0; e < 8; ++e) { p[e] = __expf(l[e] - mx); sum += p[e]; }
  float inv = 1.0f / sum;
#pragma unroll
  for (int e = 0; e < 8; ++e) p[e] *= inv;
  int i0 = 0; float v0 = p[0];
#pragma unroll
  for (int e = 1; e < 8; ++e) if (p[e] > v0) { v0 = p[e]; i0 = e; }
  int i1 = -1; float v1 = -1.0f;
#pragma unroll
  for (int e = 0; e < 8; ++e) if (e != i0 && p[e] > v1) { v1 = p[e]; i1 = e; }
  float wsum = v0 + v1;
  float g0 = v0 / wsum, g1 = v1 / wsum;
  float* gr = gates + (size_t)t * 8;
#pragma unroll
  for (int e = 0; e < 8; ++e) gr[e] = (e == i0) ? g0 : (e == i1) ? g1 : 0.0f;
#pragma unroll
  for (int e = 0; e < 8; ++e) {
    float ps = p[e];
    float cn = (e == i0 || e == i1) ? 1.0f : 0.0f;
    for (int o = 32; o; o >>= 1) { ps += __shfl_down(ps, o); cn += __shfl_down(cn, o); }
    if (lane == 0) { ax[wv][e] = ps; ax[wv][8 + e] = cn; }
  }
  __syncthreads();
  if (tid < 16)
    auxp[blockIdx.x * 16 + tid] = ax[0][tid] + ax[1][tid] + ax[2][tid] + ax[3][tid];
}

__global__ void aux_k(const float* __restrict__ auxp, float* __restrict__ out) {
  __shared__ float s[16];
  int i = threadIdx.x;
  if (i < 16) {
    float a = 0;
    for (int b = 0; b < 128; ++b) a += auxp[b * 16 + i];
    s[i] = a;
  }
  __syncthreads();
  if (i == 0) {
    float r = 0;
    for (int e = 0; e < 8; ++e)
      r += (s[8 + e] * (1.0f / 32768.0f)) * (s[e] * (1.0f / 32768.0f));
    out[0] = r * 8.0f;
  }
}

// ---------------- unified MFMA GEMM ----------------
// MODE 0: conv3x3x3 from padded buffer, y = acc + bias -> fp32
// MODE 1: moe GEMM1, h = bf16(gelu(acc + bias))
// MODE 2: moe GEMM2, moe[t][c] += gate[t]*(acc + bias)
// MODE 3: final 1x1 conv, out[oc][t] = acc + bias + xmct[oc][t]
template <int MODE>
__global__ __launch_bounds__(256, 2) void gemm_k(
    const u16* __restrict__ A, const u16* __restrict__ Bw,
    const float* __restrict__ bias, float* __restrict__ outF,
    u16* __restrict__ outB, const float* __restrict__ gatesE,
    const float* __restrict__ xmct) {
  __shared__ __attribute__((aligned(16))) unsigned char smem[32768];
  const int tid = threadIdx.x;
  const int ttile = blockIdx.x;
  const int ctile = blockIdx.y;
  const int lane = tid & 63;
  const int wv = tid >> 6;
  const int wr = (wv >> 1) << 6;
  const int wc = (wv & 1) << 6;
  const int fq = lane >> 4;
  const int fr = lane & 15;

  int aoff[4], boff[4];
#pragma unroll
  for (int it = 0; it < 4; ++it) {
    int s = tid + it * 256;
    int r = s >> 3;
    int lsg = (s & 7) ^ (r & 7);
    if (MODE == 0) {
      int dd = ttile >> 3;
      int h0 = (ttile & 7) << 2;
      int base = dd * 1156 + (h0 + (r >> 5)) * 34 + (r & 31);
      aoff[it] = base * 256 + lsg * 8;
    } else {
      aoff[it] = (ttile * 128 + r) * 256 + lsg * 8;
    }
    boff[it] = (ctile * 128 + r) * 256 + lsg * 8;
  }

  f32x4 acc[4][4];
#pragma unroll
  for (int m = 0; m < 4; ++m)
#pragma unroll
    for (int n = 0; n < 4; ++n) acc[m][n] = (f32x4){0.f, 0.f, 0.f, 0.f};

  const int nTap = (MODE == 0) ? 27 : 1;
#pragma unroll 1
  for (int tap = 0; tap < nTap; ++tap) {
    int atap = 0, btap = 0;
    if (MODE == 0) {
      atap = ((tap / 9) * 1156 + ((tap / 3) % 3) * 34 + (tap % 3)) * 256;
      btap = tap * 65536;
    }
#pragma unroll 1
    for (int kc = 0; kc < 4; ++kc) {
      const u16* Ak = A + atap + kc * 64;
      const u16* Bk = Bw + btap + kc * 64;
#pragma unroll
      for (int it = 0; it < 4; ++it) {
        __builtin_amdgcn_global_load_lds(
            (const __attribute__((address_space(1))) u32*)(Ak + aoff[it]),
            (__attribute__((address_space(3))) u32*)(smem + (tid + it * 256) * 16),
            16, 0, 0);
        __builtin_amdgcn_global_load_lds(
            (const __attribute__((address_space(1))) u32*)(Bk + boff[it]),
            (__attribute__((address_space(3))) u32*)(smem + 16384 + (tid + it * 256) * 16),
            16, 0, 0);
      }
      __syncthreads();
#pragma unroll
      for (int khf = 0; khf < 2; ++khf) {
        short8 af[4], bb[4];
#pragma unroll
        for (int m = 0; m < 4; ++m) {
          int row = wr + m * 16 + fr;
          int p = (khf * 4 + fq) ^ (row & 7);
          af[m] = *(const short8*)(smem + row * 128 + p * 16);
        }
#pragma unroll
        for (int n = 0; n < 4; ++n) {
          int row = wc + n * 16 + fr;
          int p = (khf * 4 + fq) ^ (row & 7);
          bb[n] = *(const short8*)(smem + 16384 + row * 128 + p * 16);
        }
#pragma unroll
        for (int m = 0; m < 4; ++m)
#pragma unroll
          for (int n = 0; n < 4; ++n)
            acc[m][n] = __builtin_amdgcn_mfma_f32_16x16x32_bf16(af[m], bb[n], acc[m][n], 0, 0, 0);
      }
      __syncthreads();
    }
  }

  float bs[4];
#pragma unroll
  for (int n = 0; n < 4; ++n) bs[n] = bias[ctile * 128 + wc + n * 16 + fr];

  if (MODE == 3) {
#pragma unroll
    for (int m = 0; m < 4; ++m) {
      int trow = ttile * 128 + wr + m * 16 + fq * 4;
#pragma unroll
      for (int n = 0; n < 4; ++n) {
        int oc = ctile * 128 + wc + n * 16 + fr;
        size_t o = (size_t)oc * 32768 + trow;
        float4 xv = *(const float4*)(xmct + o);
        float4 w;
        w.x = acc[m][n][0] + bs[n] + xv.x;
        w.y = acc[m][n][1] + bs[n] + xv.y;
        w.z = acc[m][n][2] + bs[n] + xv.z;
        w.w = acc[m][n][3] + bs[n] + xv.w;
        *(float4*)(outF + o) = w;
      }
    }
  } else {
#pragma unroll
    for (int m = 0; m < 4; ++m) {
#pragma unroll
      for (int j = 0; j < 4; ++j) {
        int t = ttile * 128 + wr + m * 16 + fq * 4 + j;
        size_t rowo = (size_t)t * 256 + ctile * 128 + wc;
        if (MODE == 0) {
          float* yr = outF + rowo;
#pragma unroll
          for (int n = 0; n < 4; ++n) yr[n * 16 + fr] = acc[m][n][j] + bs[n];
        } else if (MODE == 1) {
          u16* hr = outB + rowo;
#pragma unroll
          for (int n = 0; n < 4; ++n) {
            float v = acc[m][n][j] + bs[n];
            hr[n * 16 + fr] = f2bf(gelu_f(v));
          }
        } else {
          float g = gatesE[(size_t)t * 8];
          float* mr = outF + rowo;
#pragma unroll
          for (int n = 0; n < 4; ++n) mr[n * 16 + fr] += g * (acc[m][n][j] + bs[n]);
        }
      }
    }
  }
}

// ---------------- xm = x + moe: writes xm_tc (in place), xm_ct, xm_pad ----------------
__global__ void xm_k(float* __restrict__ xt, const float* __restrict__ moe,
                     float* __restrict__ xmct, u16* __restrict__ pad) {
  __shared__ float ld[64][65];
  int tt = blockIdx.x, cc = blockIdx.y, tid = threadIdx.x;
#pragma unroll
  for (int k = 0; k < 16; ++k) {
    int idx = tid + k * 256;
    int tl = idx >> 6, cl = idx & 63;
    size_t o = (size_t)(tt * 64 + tl) * 256 + cc * 64 + cl;
    float v = xt[o] + moe[o];
    xt[o] = v;
    ld[tl][cl] = v;
    int t = tt * 64 + tl;
    int d = t >> 10, h = (t >> 5) & 31, w = t & 31;
    int prow = (d + 1) * 1156 + (h + 1) * 34 + (w + 1);
    pad[(size_t)prow * 256 + cc * 64 + cl] = f2bf(v);
  }
  __syncthreads();
#pragma unroll
  for (int k = 0; k < 16; ++k) {
    int idx = tid + k * 256;
    int cl = idx >> 6, tl = idx & 63;
    xmct[(size_t)(cc * 64 + cl) * 32768 + tt * 64 + tl] = ld[tl][cl];
  }
}

// ---------------- BN stats ----------------
__global__ void stats1_k(const float* __restrict__ y, float* __restrict__ part) {
  int c = threadIdx.x, b = blockIdx.x;
  const float* yr = y + (size_t)b * 128 * 256;
  float s = 0, q = 0;
  for (int t = 0; t < 128; ++t) {
    float v = yr[t * 256 + c];
    s += v;
    q += v * v;
  }
  part[b * 256 + c] = s;
  part[65536 + b * 256 + c] = q;
}

__global__ void stats2_k(const float* __restrict__ part, const float* __restrict__ g,
                         const float* __restrict__ be, float* __restrict__ sf) {
  int c = threadIdx.x;
  float s = 0, q = 0;
  for (int b = 0; b < 256; ++b) {
    s += part[b * 256 + c];
    q += part[65536 + b * 256 + c];
  }
  float mean = s * (1.0f / 32768.0f);
  float var = q * (1.0f / 32768.0f) - mean * mean;
  float a = g[c] * rsqrtf(var + 1e-5f);
  sf[c] = a;
  sf[256 + c] = be[c] - mean * a;
}

// ---------------- BN apply (+leaky, +skip) ----------------
// V0: write padded bf16 only. V1: +skip, write padded + fp32 (r1). V2: +skip, write flat bf16 (r2).
template <int V>
__global__ void bn_k(const float* __restrict__ y, const float* __restrict__ sf,
                     const float* __restrict__ skip, u16* __restrict__ pad,
                     float* __restrict__ f32o, u16* __restrict__ bfo) {
  int gid = blockIdx.x * 256 + threadIdx.x;
  int t = gid >> 5, c0 = (gid & 31) << 3;
  size_t base = (size_t)t * 256 + c0;
  float v[8];
  const float4* yp = (const float4*)(y + base);
  float4 y0 = yp[0], y1 = yp[1];
  const float4* ap = (const float4*)(sf + c0);
  float4 a0 = ap[0], a1 = ap[1];
  const float4* shp = (const float4*)(sf + 256 + c0);
  float4 s0 = shp[0], s1 = shp[1];
  v[0] = a0.x * y0.x + s0.x; v[1] = a0.y * y0.y + s0.y;
  v[2] = a0.z * y0.z + s0.z; v[3] = a0.w * y0.w + s0.w;
  v[4] = a1.x * y1.x + s1.x; v[5] = a1.y * y1.y + s1.y;
  v[6] = a1.z * y1.z + s1.z; v[7] = a1.w * y1.w + s1.w;
  if (V >= 1) {
    const float4* kp = (const float4*)(skip + base);
    float4 k0 = kp[0], k1 = kp[1];
    v[0] += k0.x; v[1] += k0.y; v[2] += k0.z; v[3] += k0.w;
    v[4] += k1.x; v[5] += k1.y; v[6] += k1.z; v[7] += k1.w;
  }
#pragma unroll
  for (int i = 0; i < 8; ++i) v[i] = v[i] > 0.0f ? v[i] : 0.01f * v[i];
  if (V <= 1) {
    int d = t >> 10, h = (t >> 5) & 31, w = t & 31;
    int prow = (d + 1) * 1156 + (h + 1) * 34 + (w + 1);
    uint4 pk;
    pk.x = (u32)f2bf(v[0]) | ((u32)f2bf(v[1]) << 16);
    pk.y = (u32)f2bf(v[2]) | ((u32)f2bf(v[3]) << 16);
    pk.z = (u32)f2bf(v[4]) | ((u32)f2bf(v[5]) << 16);
    pk.w = (u32)f2bf(v[6]) | ((u32)f2bf(v[7]) << 16);
    *(uint4*)(pad + (size_t)prow * 256 + c0) = pk;
  }
  if (V == 1) {
    float4 o0 = {v[0], v[1], v[2], v[3]}, o1 = {v[4], v[5], v[6], v[7]};
    float4* fp = (float4*)(f32o + base);
    fp[0] = o0; fp[1] = o1;
  }
  if (V == 2) {
    uint4 pk;
    pk.x = (u32)f2bf(v[0]) | ((u32)f2bf(v[1]) << 16);
    pk.y = (u32)f2bf(v[2]) | ((u32)f2bf(v[3]) << 16);
    pk.z = (u32)f2bf(v[4]) | ((u32)f2bf(v[5]) << 16);
    pk.w = (u32)f2bf(v[6]) | ((u32)f2bf(v[7]) << 16);
    *(uint4*)(bfo + base) = pk;
  }
}

extern "C" void kernel_launch(void* const* d_in, const int* in_sizes, int n_in,
                              void* d_out, int out_size, void* d_ws, size_t ws_size,
                              hipStream_t stream) {
  (void)in_sizes; (void)n_in; (void)out_size; (void)ws_size;
  const float* x  = (const float*)d_in[0];
  const float* wg = (const float*)d_in[1];
  const float* w1 = (const float*)d_in[2];
  const float* b1 = (const float*)d_in[3];
  const float* w2 = (const float*)d_in[4];
  const float* b2 = (const float*)d_in[5];

  char* ws = (char*)d_ws;
  u16* tok    = (u16*)(ws + WS_TOK);
  float* xt   = (float*)(ws + WS_XT);
  float* xmct = (float*)(ws + WS_XMCT);
  float* gates= (float*)(ws + WS_GATES);
  u16* hbuf   = (u16*)(ws + WS_H);
  float* moe  = (float*)(ws + WS_MOE);
  u16* P1     = (u16*)(ws + WS_P1);
  u16* P2     = (u16*)(ws + WS_P2);
  float* ybuf = (float*)(ws + WS_Y);
  u16* r2b    = (u16*)(ws + WS_R2);
  u16* wrb    = (u16*)(ws + WS_WRB);
  u16* w1p    = (u16*)(ws + WS_W1P);
  u16* w2p    = (u16*)(ws + WS_W2P);
  u16* c8p    = (u16*)(ws + WS_C8P);
  float* part = (float*)(ws + WS_PART);
  float* sf   = (float*)(ws + WS_SF);
  float* auxp = (float*)(ws + WS_AUXP);
  float* outp = (float*)d_out;

  hipMemsetAsync(P1, 0, 20123648, stream);
  hipMemsetAsync(P2, 0, 20123648, stream);
  hipMemsetAsync(moe, 0, 33554432, stream);

  trans_in_k<<<dim3(512, 4), 256, 0, stream>>>(x, xt, tok);
  pack_rb_k<<<1024, 256, 0, stream>>>((const float*)d_in[6], (const float*)d_in[10],
                                      (const float*)d_in[14], (const float*)d_in[18], wrb);
  pack_tr_k<<<dim3(16, 16), 256, 0, stream>>>(w1, w2, w1p, w2p);
  cvt_k<<<256, 256, 0, stream>>>((const float*)d_in[22], c8p, 65536);
  gate_k<<<128, 256, 0, stream>>>(xt, wg, gates, auxp);

  for (int e = 0; e < 8; ++e) {
    gemm_k<1><<<dim3(256, 2), 256, 0, stream>>>(tok, w1p + e * 65536, b1 + e * 256,
                                                nullptr, hbuf, nullptr, nullptr);
    gemm_k<2><<<dim3(256, 2), 256, 0, stream>>>(hbuf, w2p + e * 65536, b2 + e * 256,
                                                moe, nullptr, gates + e, nullptr);
  }
  xm_k<<<dim3(512, 4), 256, 0, stream>>>(xt, moe, xmct, P1);

  // resblock 1
  gemm_k<0><<<dim3(256, 2), 256, 0, stream>>>(P1, wrb + 0 * 1769472, (const float*)d_in[7],
                                              ybuf, nullptr, nullptr, nullptr);
  stats1_k<<<256, 256, 0, stream>>>(ybuf, part);
  stats2_k<<<1, 256, 0, stream>>>(part, (const float*)d_in[8], (const float*)d_in[9], sf);
  bn_k<0><<<4096, 256, 0, stream>>>(ybuf, sf, nullptr, P2, nullptr, nullptr);
  gemm_k<0><<<dim3(256, 2), 256, 0, stream>>>(P2, wrb + 1 * 1769472, (const float*)d_in[11],
                                              ybuf, nullptr, nullptr, nullptr);
  stats1_k<<<256, 256, 0, stream>>>(ybuf, part);
  stats2_k<<<1, 256, 0, stream>>>(part, (const float*)d_in[12], (const float*)d_in[13], sf);
  bn_k<1><<<4096, 256, 0, stream>>>(ybuf, sf, xt, P1, xt, nullptr);

  // resblock 2
  gemm_k<0><<<dim3(256, 2), 256, 0, stream>>>(P1, wrb + 2 * 1769472, (const float*)d_in[15],
                                              ybuf, nullptr, nullptr, nullptr);
  stats1_k<<<256, 256, 0, stream>>>(ybuf, part);
  stats2_k<<<1, 256, 0, stream>>>(part, (const float*)d_in[16], (const float*)d_in[17], sf);
  bn_k<0><<<4096, 256, 0, stream>>>(ybuf, sf, nullptr, P2, nullptr, nullptr);
  gemm_k<0><<<dim3(256, 2), 256, 0, stream>>>(P2, wrb + 3 * 1769472, (const float*)d_in[19],
                                              ybuf, nullptr, nullptr, nullptr);
  stats1_k<<<256, 256, 0, stream>>>(ybuf, part);
  stats2_k<<<1, 256, 0, stream>>>(part, (const float*)d_in[20], (const float*)d_in[21], sf);
  bn_k<2><<<4096, 256, 0, stream>>>(ybuf, sf, xt, nullptr, nullptr, r2b);

  // final: out = xm + conv1x1(res)
  gemm_k<3><<<dim3(256, 2), 256, 0, stream>>>(r2b, c8p, (const float*)d_in[23], outp,
                                              nullptr, nullptr, xmct);
  aux_k<<<1, 64, 0, stream>>>(auxp, outp + 8388608);
}

// Round 2
// 815.257 us; speedup vs baseline: 1.1633x; 1.1633x over previous
//
#include <hip/hip_runtime.h>
#include <stdint.h>

typedef __attribute__((ext_vector_type(8))) short short8;
typedef __attribute__((ext_vector_type(4))) float f32x4;
typedef unsigned short u16;
typedef unsigned int u32;

// ---------------- workspace layout (bytes) ----------------
#define WS_TOK   0ull           // tokens bf16 [32768][256]            16 MB
#define WS_XT    16777216ull    // x_t -> xm_tc -> r1 fp32 [T][C]      32 MB
#define WS_XMCT  50331648ull    // xm fp32 [C][T]                      32 MB
#define WS_GATES 83886080ull    // gates fp32 [T][8]                    1 MB
#define WS_H     84934656ull    // (unused now)                        16 MB
#define WS_MOE   101711872ull   // moe fp32 [T][256]                   32 MB
#define WS_P1    135266304ull   // padded bf16 [34^3][256]             19.2MB
#define WS_P2    155389952ull
#define WS_Y     175513600ull   // conv out fp32 [T][256]              32 MB
#define WS_R2    209068032ull   // r2 bf16 [T][256]                    16 MB
#define WS_WRB   225845248ull   // packed rb conv w bf16 [4][27][256][256]
#define WS_W1P   240001024ull   // w1 packed bf16 [8][256][256]
#define WS_W2P   241049600ull
#define WS_C8P   242098176ull
#define WS_PART  242229248ull   // bn partials [2][256][256] fp32
#define WS_SF    242753536ull   // bn scale/shift [2][256]
#define WS_AUXP  242755584ull   // aux partials [128][16]

__device__ __forceinline__ u16 f2bf(float f) {
  u32 x = __float_as_uint(f);
  u32 r = x + 0x7fffu + ((x >> 16) & 1u);
  return (u16)(r >> 16);
}

// ---------------- transpose x [C][T] -> x_t fp32 + tokens bf16 [T][C] ----------------
__global__ void trans_in_k(const float* __restrict__ x, float* __restrict__ xt,
                           u16* __restrict__ tok) {
  __shared__ float ld[64][65];
  int tt = blockIdx.x, cc = blockIdx.y, tid = threadIdx.x;
#pragma unroll
  for (int k = 0; k < 16; ++k) {
    int idx = tid + k * 256;
    int cl = idx >> 6, j = idx & 63;
    ld[cl][j] = x[(size_t)(cc * 64 + cl) * 32768 + tt * 64 + j];
  }
  __syncthreads();
#pragma unroll
  for (int k = 0; k < 16; ++k) {
    int idx = tid + k * 256;
    int tl = idx >> 6, cl = idx & 63;
    float v = ld[cl][tl];
    size_t o = (size_t)(tt * 64 + tl) * 256 + cc * 64 + cl;
    xt[o] = v;
    tok[o] = f2bf(v);
  }
}

// ---------------- pack resblock conv weights ----------------
__global__ void pack_rb_k(const float* __restrict__ w0, const float* __restrict__ w1,
                          const float* __restrict__ w2, const float* __restrict__ w3,
                          u16* __restrict__ out) {
  __shared__ float ld[6912];
  int conv = blockIdx.x >> 8, blk = blockIdx.x & 255, tid = threadIdx.x;
  const float* src = conv == 0 ? w0 : conv == 1 ? w1 : conv == 2 ? w2 : w3;
  size_t base = (size_t)blk * 256 * 27;
#pragma unroll
  for (int k = 0; k < 27; ++k) ld[tid + k * 256] = src[base + tid + k * 256];
  __syncthreads();
  u16* dst = out + (size_t)conv * 27 * 65536;
  int n = blk * 256 + tid;
#pragma unroll
  for (int tap = 0; tap < 27; ++tap)
    dst[(size_t)tap * 65536 + n] = f2bf(ld[tid * 27 + tap]);
}

// ---------------- transpose-pack w1/w2 256x256 matrices to [N][K] bf16 ----------------
__global__ void pack_tr_k(const float* __restrict__ w1, const float* __restrict__ w2,
                          u16* __restrict__ w1p, u16* __restrict__ w2p) {
  __shared__ float ld[64][65];
  int m = blockIdx.y, tile = blockIdx.x, tid = threadIdx.x;
  const float* src = (m < 8) ? (w1 + (size_t)m * 65536) : (w2 + (size_t)(m - 8) * 65536);
  u16* dst = (m < 8) ? (w1p + (size_t)m * 65536) : (w2p + (size_t)(m - 8) * 65536);
  int r0 = (tile >> 2) * 64, c0 = (tile & 3) * 64;
#pragma unroll
  for (int k = 0; k < 16; ++k) {
    int idx = tid + k * 256;
    int rr = idx >> 6, cc = idx & 63;
    ld[rr][cc] = src[(size_t)(r0 + rr) * 256 + c0 + cc];
  }
  __syncthreads();
#pragma unroll
  for (int k = 0; k < 16; ++k) {
    int idx = tid + k * 256;
    int cc = idx >> 6, rr = idx & 63;
    dst[(size_t)(c0 + cc) * 256 + r0 + rr] = f2bf(ld[rr][cc]);
  }
}

__global__ void cvt_k(const float* __restrict__ in, u16* __restrict__ out, int n) {
  int i = blockIdx.x * 256 + threadIdx.x;
  if (i < n) out[i] = f2bf(in[i]);
}

// ---------------- zero halo rows of both padded buffers ----------------
__global__ void halo_k(u16* __restrict__ P1, u16* __restrict__ P2) {
  int gid = blockIdx.x * 256 + threadIdx.x;
  int r = gid >> 5, o = (gid & 31) << 3;
  if (r >= 39304) return;
  int d = r / 1156, rem = r - d * 1156, h = rem / 34, w = rem - h * 34;
  if (d >= 1 && d <= 32 && h >= 1 && h <= 32 && w >= 1 && w <= 32) return;
  uint4 z = {0u, 0u, 0u, 0u};
  *(uint4*)(P1 + (size_t)r * 256 + o) = z;
  *(uint4*)(P2 + (size_t)r * 256 + o) = z;
}

// ---------------- gating: softmax + top2 + aux partials ----------------
__global__ void gate_k(const float* __restrict__ xt, const float* __restrict__ wg,
                       float* __restrict__ gates, float* __restrict__ auxp) {
  __shared__ float wgs[2048];
  __shared__ float ax[4][16];
  int tid = threadIdx.x;
#pragma unroll
  for (int k = 0; k < 8; ++k) wgs[tid + k * 256] = wg[tid + k * 256];
  __syncthreads();
  int t = blockIdx.x * 256 + tid;
  int lane = tid & 63, wv = tid >> 6;
  float l[8] = {0, 0, 0, 0, 0, 0, 0, 0};
  const float* xr = xt + (size_t)t * 256;
  for (int c = 0; c < 256; c += 4) {
    float4 xv = *(const float4*)(xr + c);
#pragma unroll
    for (int e = 0; e < 8; ++e)
      l[e] += xv.x * wgs[c * 8 + e] + xv.y * wgs[(c + 1) * 8 + e] +
              xv.z * wgs[(c + 2) * 8 + e] + xv.w * wgs[(c + 3) * 8 + e];
  }
  float mx = l[0];
#pragma unroll
  for (int e = 1; e < 8; ++e) mx = fmaxf(mx, l[e]);
  float p[8], sum = 0.f;
#pragma unroll
  for (int e = 0; e < 8; ++e) { p[e] = __expf(l[e] - mx); sum += p[e]; }
  float inv = 1.0f / sum;
#pragma unroll
  for (int e = 0; e < 8; ++e) p[e] *= inv;
  int i0 = 0; float v0 = p[0];
#pragma unroll
  for (int e = 1; e < 8; ++e) if (p[e] > v0) { v0 = p[e]; i0 = e; }
  int i1 = -1; float v1 = -1.0f;
#pragma unroll
  for (int e = 0; e < 8; ++e) if (e != i0 && p[e] > v1) { v1 = p[e]; i1 = e; }
  float wsum = v0 + v1;
  float g0 = v0 / wsum, g1 = v1 / wsum;
  float* gr = gates + (size_t)t * 8;
#pragma unroll
  for (int e = 0; e < 8; ++e) gr[e] = (e == i0) ? g0 : (e == i1) ? g1 : 0.0f;
#pragma unroll
  for (int e = 0; e < 8; ++e) {
    float ps = p[e];
    float cn = (e == i0 || e == i1) ? 1.0f : 0.0f;
    for (int o = 32; o; o >>= 1) { ps += __shfl_down(ps, o); cn += __shfl_down(cn, o); }
    if (lane == 0) { ax[wv][e] = ps; ax[wv][8 + e] = cn; }
  }
  __syncthreads();
  if (tid < 16)
    auxp[blockIdx.x * 16 + tid] = ax[0][tid] + ax[1][tid] + ax[2][tid] + ax[3][tid];
}

__global__ void aux_k(const float* __restrict__ auxp, float* __restrict__ out) {
  __shared__ float s[16];
  int i = threadIdx.x;
  if (i < 16) {
    float a = 0;
    for (int b = 0; b < 128; ++b) a += auxp[b * 16 + i];
    s[i] = a;
  }
  __syncthreads();
  if (i == 0) {
    float r = 0;
    for (int e = 0; e < 8; ++e)
      r += (s[8 + e] * (1.0f / 32768.0f)) * (s[e] * (1.0f / 32768.0f));
    out[0] = r * 8.0f;
  }
}

// ---------------- fused MoE: all 8 experts, h in LDS, one dispatch ----------------
// block: 512 threads, tile = 128 tokens x 256 cols. LDS: As 64KB | Bs 32KB | Hs 64KB.
__global__ __launch_bounds__(512, 2) void moe_k(
    const u16* __restrict__ tok, const u16* __restrict__ w1p,
    const u16* __restrict__ w2p, const float* __restrict__ b1,
    const float* __restrict__ b2, const float* __restrict__ gates,
    float* __restrict__ moe) {
  __shared__ __attribute__((aligned(16))) unsigned char smem[163840];
  const int tid = threadIdx.x;
  const int ttile = blockIdx.x;
  const int lane = tid & 63;
  const int wv = tid >> 6;
  const int wr = (wv >> 2) * 64;
  const int wc = (wv & 3) * 64;
  const int fq = lane >> 4;
  const int fr = lane & 15;

  // stage tok tile [128][256] once (seg-swizzled source, linear LDS dest)
#pragma unroll
  for (int it = 0; it < 8; ++it) {
    int s = tid + it * 512;
    int r = s >> 5, seg = s & 31;
    int col = (seg >> 3) * 64 + (((seg & 7) ^ (r & 7)) << 3);
    __builtin_amdgcn_global_load_lds(
        (const __attribute__((address_space(1))) u32*)(tok + (size_t)(ttile * 128 + r) * 256 + col),
        (__attribute__((address_space(3))) u32*)(smem + s * 16), 16, 0, 0);
  }

  f32x4 macc[4][4];
#pragma unroll
  for (int m = 0; m < 4; ++m)
#pragma unroll
    for (int n = 0; n < 4; ++n) macc[m][n] = (f32x4){0.f, 0.f, 0.f, 0.f};

#pragma unroll 1
  for (int e = 0; e < 8; ++e) {
    const u16* w1e = w1p + e * 65536;
    const u16* w2e = w2p + e * 65536;

    // ---- GEMM1: h = gelu(tok @ w1e^T + b1) ----
    f32x4 acc1[4][4];
#pragma unroll
    for (int m = 0; m < 4; ++m)
#pragma unroll
      for (int n = 0; n < 4; ++n) acc1[m][n] = (f32x4){0.f, 0.f, 0.f, 0.f};

#pragma unroll 1
    for (int kc = 0; kc < 4; ++kc) {
#pragma unroll
      for (int it = 0; it < 4; ++it) {
        int s = tid + it * 512;
        int r = s >> 3;
        int sub = (s & 7) ^ (r & 7);
        __builtin_amdgcn_global_load_lds(
            (const __attribute__((address_space(1))) u32*)(w1e + (size_t)r * 256 + kc * 64 + sub * 8),
            (__attribute__((address_space(3))) u32*)(smem + 65536 + s * 16), 16, 0, 0);
      }
      __syncthreads();
#pragma unroll
      for (int khf = 0; khf < 2; ++khf) {
        short8 af[4], bb[4];
#pragma unroll
        for (int m = 0; m < 4; ++m) {
          int row = wr + m * 16 + fr;
          int sub = (khf * 4 + fq) ^ (row & 7);
          af[m] = *(const short8*)(smem + row * 512 + kc * 128 + sub * 16);
        }
#pragma unroll
        for (int n = 0; n < 4; ++n) {
          int row = wc + n * 16 + fr;
          int p = (khf * 4 + fq) ^ (row & 7);
          bb[n] = *(const short8*)(smem + 65536 + row * 128 + p * 16);
        }
#pragma unroll
        for (int m = 0; m < 4; ++m)
#pragma unroll
          for (int n = 0; n < 4; ++n)
            acc1[m][n] = __builtin_amdgcn_mfma_f32_16x16x32_bf16(af[m], bb[n], acc1[m][n], 0, 0, 0);
      }
      __syncthreads();
    }

    // epilogue: bias + gelu -> Hs (bf16, swizzled)
    float bs1[4];
#pragma unroll
    for (int n = 0; n < 4; ++n) bs1[n] = b1[e * 256 + wc + n * 16 + fr];
#pragma unroll
    for (int m = 0; m < 4; ++m)
#pragma unroll
      for (int n = 0; n < 4; ++n)
#pragma unroll
        for (int j = 0; j < 4; ++j) {
          int row = wr + m * 16 + fq * 4 + j;
          int c = wc + n * 16 + fr;
          float v = acc1[m][n][j] + bs1[n];
          float u = 1.5957691216057308f * (v + 0.044715f * v * v * v);
          float sg = 1.0f / (1.0f + __expf(-u));
          int sub = ((c >> 3) & 7) ^ (row & 7);
          *(u16*)(smem + 98304 + row * 512 + (c >> 6) * 128 + sub * 16 + (c & 7) * 2) =
              f2bf(v * sg);
        }

    // ---- GEMM2: eo = h @ w2e^T + b2; macc += gate * eo ----
    f32x4 acc2[4][4];
#pragma unroll
    for (int m = 0; m < 4; ++m)
#pragma unroll
      for (int n = 0; n < 4; ++n) acc2[m][n] = (f32x4){0.f, 0.f, 0.f, 0.f};

#pragma unroll 1
    for (int kc = 0; kc < 4; ++kc) {
#pragma unroll
      for (int it = 0; it < 4; ++it) {
        int s = tid + it * 512;
        int r = s >> 3;
        int sub = (s & 7) ^ (r & 7);
        __builtin_amdgcn_global_load_lds(
            (const __attribute__((address_space(1))) u32*)(w2e + (size_t)r * 256 + kc * 64 + sub * 8),
            (__attribute__((address_space(3))) u32*)(smem + 65536 + s * 16), 16, 0, 0);
      }
      __syncthreads();  // publishes Hs writes (lgkm) + Bs2 (vm)
#pragma unroll
      for (int khf = 0; khf < 2; ++khf) {
        short8 af[4], bb[4];
#pragma unroll
        for (int m = 0; m < 4; ++m) {
          int row = wr + m * 16 + fr;
          int sub = (khf * 4 + fq) ^ (row & 7);
          af[m] = *(const short8*)(smem + 98304 + row * 512 + kc * 128 + sub * 16);
        }
#pragma unroll
        for (int n = 0; n < 4; ++n) {
          int row = wc + n * 16 + fr;
          int p = (khf * 4 + fq) ^ (row & 7);
          bb[n] = *(const short8*)(smem + 65536 + row * 128 + p * 16);
        }
#pragma unroll
        for (int m = 0; m < 4; ++m)
#pragma unroll
          for (int n = 0; n < 4; ++n)
            acc2[m][n] = __builtin_amdgcn_mfma_f32_16x16x32_bf16(af[m], bb[n], acc2[m][n], 0, 0, 0);
      }
      __syncthreads();
    }

    float bs2[4];
#pragma unroll
    for (int n = 0; n < 4; ++n) bs2[n] = b2[e * 256 + wc + n * 16 + fr];
#pragma unroll
    for (int m = 0; m < 4; ++m)
#pragma unroll
      for (int j = 0; j < 4; ++j) {
        int t = ttile * 128 + wr + m * 16 + fq * 4 + j;
        float g = gates[(size_t)t * 8 + e];
#pragma unroll
        for (int n = 0; n < 4; ++n)
          macc[m][n][j] += g * (acc2[m][n][j] + bs2[n]);
      }
  }

  // write moe
#pragma unroll
  for (int m = 0; m < 4; ++m)
#pragma unroll
    for (int j = 0; j < 4; ++j) {
      int t = ttile * 128 + wr + m * 16 + fq * 4 + j;
      float* mr = moe + (size_t)t * 256 + wc;
#pragma unroll
      for (int n = 0; n < 4; ++n) mr[n * 16 + fr] = macc[m][n][j];
    }
}

// ---------------- unified MFMA GEMM (convs + final 1x1) ----------------
// MODE 0: conv3x3x3 from padded buffer, y = acc + bias -> fp32
// MODE 3: final 1x1 conv, out[oc][t] = acc + bias + xmct[oc][t]
template <int MODE>
__global__ __launch_bounds__(256, 2) void gemm_k(
    const u16* __restrict__ A, const u16* __restrict__ Bw,
    const float* __restrict__ bias, float* __restrict__ outF,
    u16* __restrict__ outB, const float* __restrict__ gatesE,
    const float* __restrict__ xmct) {
  __shared__ __attribute__((aligned(16))) unsigned char smem[32768];
  const int tid = threadIdx.x;
  const int ttile = blockIdx.x;
  const int ctile = blockIdx.y;
  const int lane = tid & 63;
  const int wv = tid >> 6;
  const int wr = (wv >> 1) << 6;
  const int wc = (wv & 1) << 6;
  const int fq = lane >> 4;
  const int fr = lane & 15;

  int aoff[4], boff[4];
#pragma unroll
  for (int it = 0; it < 4; ++it) {
    int s = tid + it * 256;
    int r = s >> 3;
    int lsg = (s & 7) ^ (r & 7);
    if (MODE == 0) {
      int dd = ttile >> 3;
      int h0 = (ttile & 7) << 2;
      int base = dd * 1156 + (h0 + (r >> 5)) * 34 + (r & 31);
      aoff[it] = base * 256 + lsg * 8;
    } else {
      aoff[it] = (ttile * 128 + r) * 256 + lsg * 8;
    }
    boff[it] = (ctile * 128 + r) * 256 + lsg * 8;
  }

  f32x4 acc[4][4];
#pragma unroll
  for (int m = 0; m < 4; ++m)
#pragma unroll
    for (int n = 0; n < 4; ++n) acc[m][n] = (f32x4){0.f, 0.f, 0.f, 0.f};

  const int nTap = (MODE == 0) ? 27 : 1;
#pragma unroll 1
  for (int tap = 0; tap < nTap; ++tap) {
    int atap = 0, btap = 0;
    if (MODE == 0) {
      atap = ((tap / 9) * 1156 + ((tap / 3) % 3) * 34 + (tap % 3)) * 256;
      btap = tap * 65536;
    }
#pragma unroll 1
    for (int kc = 0; kc < 4; ++kc) {
      const u16* Ak = A + atap + kc * 64;
      const u16* Bk = Bw + btap + kc * 64;
#pragma unroll
      for (int it = 0; it < 4; ++it) {
        __builtin_amdgcn_global_load_lds(
            (const __attribute__((address_space(1))) u32*)(Ak + aoff[it]),
            (__attribute__((address_space(3))) u32*)(smem + (tid + it * 256) * 16),
            16, 0, 0);
        __builtin_amdgcn_global_load_lds(
            (const __attribute__((address_space(1))) u32*)(Bk + boff[it]),
            (__attribute__((address_space(3))) u32*)(smem + 16384 + (tid + it * 256) * 16),
            16, 0, 0);
      }
      __syncthreads();
#pragma unroll
      for (int khf = 0; khf < 2; ++khf) {
        short8 af[4], bb[4];
#pragma unroll
        for (int m = 0; m < 4; ++m) {
          int row = wr + m * 16 + fr;
          int p = (khf * 4 + fq) ^ (row & 7);
          af[m] = *(const short8*)(smem + row * 128 + p * 16);
        }
#pragma unroll
        for (int n = 0; n < 4; ++n) {
          int row = wc + n * 16 + fr;
          int p = (khf * 4 + fq) ^ (row & 7);
          bb[n] = *(const short8*)(smem + 16384 + row * 128 + p * 16);
        }
#pragma unroll
        for (int m = 0; m < 4; ++m)
#pragma unroll
          for (int n = 0; n < 4; ++n)
            acc[m][n] = __builtin_amdgcn_mfma_f32_16x16x32_bf16(af[m], bb[n], acc[m][n], 0, 0, 0);
      }
      __syncthreads();
    }
  }

  float bs[4];
#pragma unroll
  for (int n = 0; n < 4; ++n) bs[n] = bias[ctile * 128 + wc + n * 16 + fr];

  if (MODE == 3) {
#pragma unroll
    for (int m = 0; m < 4; ++m) {
      int trow = ttile * 128 + wr + m * 16 + fq * 4;
#pragma unroll
      for (int n = 0; n < 4; ++n) {
        int oc = ctile * 128 + wc + n * 16 + fr;
        size_t o = (size_t)oc * 32768 + trow;
        float4 xv = *(const float4*)(xmct + o);
        float4 w;
        w.x = acc[m][n][0] + bs[n] + xv.x;
        w.y = acc[m][n][1] + bs[n] + xv.y;
        w.z = acc[m][n][2] + bs[n] + xv.z;
        w.w = acc[m][n][3] + bs[n] + xv.w;
        *(float4*)(outF + o) = w;
      }
    }
  } else {
#pragma unroll
    for (int m = 0; m < 4; ++m) {
#pragma unroll
      for (int j = 0; j < 4; ++j) {
        int t = ttile * 128 + wr + m * 16 + fq * 4 + j;
        size_t rowo = (size_t)t * 256 + ctile * 128 + wc;
        float* yr = outF + rowo;
#pragma unroll
        for (int n = 0; n < 4; ++n) yr[n * 16 + fr] = acc[m][n][j] + bs[n];
      }
    }
  }
}

// ---------------- xm = x + moe: writes xm_tc (in place), xm_ct, xm_pad ----------------
__global__ void xm_k(float* __restrict__ xt, const float* __restrict__ moe,
                     float* __restrict__ xmct, u16* __restrict__ pad) {
  __shared__ float ld[64][65];
  int tt = blockIdx.x, cc = blockIdx.y, tid = threadIdx.x;
#pragma unroll
  for (int k = 0; k < 16; ++k) {
    int idx = tid + k * 256;
    int tl = idx >> 6, cl = idx & 63;
    size_t o = (size_t)(tt * 64 + tl) * 256 + cc * 64 + cl;
    float v = xt[o] + moe[o];
    xt[o] = v;
    ld[tl][cl] = v;
    int t = tt * 64 + tl;
    int d = t >> 10, h = (t >> 5) & 31, w = t & 31;
    int prow = (d + 1) * 1156 + (h + 1) * 34 + (w + 1);
    pad[(size_t)prow * 256 + cc * 64 + cl] = f2bf(v);
  }
  __syncthreads();
#pragma unroll
  for (int k = 0; k < 16; ++k) {
    int idx = tid + k * 256;
    int cl = idx >> 6, tl = idx & 63;
    xmct[(size_t)(cc * 64 + cl) * 32768 + tt * 64 + tl] = ld[tl][cl];
  }
}

// ---------------- BN stats ----------------
__global__ void stats1_k(const float* __restrict__ y, float* __restrict__ part) {
  int c = threadIdx.x, b = blockIdx.x;
  const float* yr = y + (size_t)b * 128 * 256;
  float s = 0, q = 0;
  for (int t = 0; t < 128; ++t) {
    float v = yr[t * 256 + c];
    s += v;
    q += v * v;
  }
  part[b * 256 + c] = s;
  part[65536 + b * 256 + c] = q;
}

__global__ void stats2_k(const float* __restrict__ part, const float* __restrict__ g,
                         const float* __restrict__ be, float* __restrict__ sf) {
  int c = threadIdx.x;
  float s = 0, q = 0;
  for (int b = 0; b < 256; ++b) {
    s += part[b * 256 + c];
    q += part[65536 + b * 256 + c];
  }
  float mean = s * (1.0f / 32768.0f);
  float var = q * (1.0f / 32768.0f) - mean * mean;
  float a = g[c] * rsqrtf(var + 1e-5f);
  sf[c] = a;
  sf[256 + c] = be[c] - mean * a;
}

// ---------------- BN apply (+leaky, +skip) ----------------
template <int V>
__global__ void bn_k(const float* __restrict__ y, const float* __restrict__ sf,
                     const float* __restrict__ skip, u16* __restrict__ pad,
                     float* __restrict__ f32o, u16* __restrict__ bfo) {
  int gid = blockIdx.x * 256 + threadIdx.x;
  int t = gid >> 5, c0 = (gid & 31) << 3;
  size_t base = (size_t)t * 256 + c0;
  float v[8];
  const float4* yp = (const float4*)(y + base);
  float4 y0 = yp[0], y1 = yp[1];
  const float4* ap = (const float4*)(sf + c0);
  float4 a0 = ap[0], a1 = ap[1];
  const float4* shp = (const float4*)(sf + 256 + c0);
  float4 s0 = shp[0], s1 = shp[1];
  v[0] = a0.x * y0.x + s0.x; v[1] = a0.y * y0.y + s0.y;
  v[2] = a0.z * y0.z + s0.z; v[3] = a0.w * y0.w + s0.w;
  v[4] = a1.x * y1.x + s1.x; v[5] = a1.y * y1.y + s1.y;
  v[6] = a1.z * y1.z + s1.z; v[7] = a1.w * y1.w + s1.w;
  if (V >= 1) {
    const float4* kp = (const float4*)(skip + base);
    float4 k0 = kp[0], k1 = kp[1];
    v[0] += k0.x; v[1] += k0.y; v[2] += k0.z; v[3] += k0.w;
    v[4] += k1.x; v[5] += k1.y; v[6] += k1.z; v[7] += k1.w;
  }
#pragma unroll
  for (int i = 0; i < 8; ++i) v[i] = v[i] > 0.0f ? v[i] : 0.01f * v[i];
  if (V <= 1) {
    int d = t >> 10, h = (t >> 5) & 31, w = t & 31;
    int prow = (d + 1) * 1156 + (h + 1) * 34 + (w + 1);
    uint4 pk;
    pk.x = (u32)f2bf(v[0]) | ((u32)f2bf(v[1]) << 16);
    pk.y = (u32)f2bf(v[2]) | ((u32)f2bf(v[3]) << 16);
    pk.z = (u32)f2bf(v[4]) | ((u32)f2bf(v[5]) << 16);
    pk.w = (u32)f2bf(v[6]) | ((u32)f2bf(v[7]) << 16);
    *(uint4*)(pad + (size_t)prow * 256 + c0) = pk;
  }
  if (V == 1) {
    float4 o0 = {v[0], v[1], v[2], v[3]}, o1 = {v[4], v[5], v[6], v[7]};
    float4* fp = (float4*)(f32o + base);
    fp[0] = o0; fp[1] = o1;
  }
  if (V == 2) {
    uint4 pk;
    pk.x = (u32)f2bf(v[0]) | ((u32)f2bf(v[1]) << 16);
    pk.y = (u32)f2bf(v[2]) | ((u32)f2bf(v[3]) << 16);
    pk.z = (u32)f2bf(v[4]) | ((u32)f2bf(v[5]) << 16);
    pk.w = (u32)f2bf(v[6]) | ((u32)f2bf(v[7]) << 16);
    *(uint4*)(bfo + base) = pk;
  }
}

extern "C" void kernel_launch(void* const* d_in, const int* in_sizes, int n_in,
                              void* d_out, int out_size, void* d_ws, size_t ws_size,
                              hipStream_t stream) {
  (void)in_sizes; (void)n_in; (void)out_size; (void)ws_size;
  const float* x  = (const float*)d_in[0];
  const float* wg = (const float*)d_in[1];
  const float* w1 = (const float*)d_in[2];
  const float* b1 = (const float*)d_in[3];
  const float* w2 = (const float*)d_in[4];
  const float* b2 = (const float*)d_in[5];

  char* ws = (char*)d_ws;
  u16* tok    = (u16*)(ws + WS_TOK);
  float* xt   = (float*)(ws + WS_XT);
  float* xmct = (float*)(ws + WS_XMCT);
  float* gates= (float*)(ws + WS_GATES);
  float* moe  = (float*)(ws + WS_MOE);
  u16* P1     = (u16*)(ws + WS_P1);
  u16* P2     = (u16*)(ws + WS_P2);
  float* ybuf = (float*)(ws + WS_Y);
  u16* r2b    = (u16*)(ws + WS_R2);
  u16* wrb    = (u16*)(ws + WS_WRB);
  u16* w1p    = (u16*)(ws + WS_W1P);
  u16* w2p    = (u16*)(ws + WS_W2P);
  u16* c8p    = (u16*)(ws + WS_C8P);
  float* part = (float*)(ws + WS_PART);
  float* sf   = (float*)(ws + WS_SF);
  float* auxp = (float*)(ws + WS_AUXP);
  float* outp = (float*)d_out;

  halo_k<<<4913, 256, 0, stream>>>(P1, P2);
  trans_in_k<<<dim3(512, 4), 256, 0, stream>>>(x, xt, tok);
  pack_rb_k<<<1024, 256, 0, stream>>>((const float*)d_in[6], (const float*)d_in[10],
                                      (const float*)d_in[14], (const float*)d_in[18], wrb);
  pack_tr_k<<<dim3(16, 16), 256, 0, stream>>>(w1, w2, w1p, w2p);
  cvt_k<<<256, 256, 0, stream>>>((const float*)d_in[22], c8p, 65536);
  gate_k<<<128, 256, 0, stream>>>(xt, wg, gates, auxp);

  moe_k<<<256, 512, 0, stream>>>(tok, w1p, w2p, b1, b2, gates, moe);
  xm_k<<<dim3(512, 4), 256, 0, stream>>>(xt, moe, xmct, P1);

  // resblock 1
  gemm_k<0><<<dim3(256, 2), 256, 0, stream>>>(P1, wrb + 0 * 1769472, (const float*)d_in[7],
                                              ybuf, nullptr, nullptr, nullptr);
  stats1_k<<<256, 256, 0, stream>>>(ybuf, part);
  stats2_k<<<1, 256, 0, stream>>>(part, (const float*)d_in[8], (const float*)d_in[9], sf);
  bn_k<0><<<4096, 256, 0, stream>>>(ybuf, sf, nullptr, P2, nullptr, nullptr);
  gemm_k<0><<<dim3(256, 2), 256, 0, stream>>>(P2, wrb + 1 * 1769472, (const float*)d_in[11],
                                              ybuf, nullptr, nullptr, nullptr);
  stats1_k<<<256, 256, 0, stream>>>(ybuf, part);
  stats2_k<<<1, 256, 0, stream>>>(part, (const float*)d_in[12], (const float*)d_in[13], sf);
  bn_k<1><<<4096, 256, 0, stream>>>(ybuf, sf, xt, P1, xt, nullptr);

  // resblock 2
  gemm_k<0><<<dim3(256, 2), 256, 0, stream>>>(P1, wrb + 2 * 1769472, (const float*)d_in[15],
                                              ybuf, nullptr, nullptr, nullptr);
  stats1_k<<<256, 256, 0, stream>>>(ybuf, part);
  stats2_k<<<1, 256, 0, stream>>>(part, (const float*)d_in[16], (const float*)d_in[17], sf);
  bn_k<0><<<4096, 256, 0, stream>>>(ybuf, sf, nullptr, P2, nullptr, nullptr);
  gemm_k<0><<<dim3(256, 2), 256, 0, stream>>>(P2, wrb + 3 * 1769472, (const float*)d_in[19],
                                              ybuf, nullptr, nullptr, nullptr);
  stats1_k<<<256, 256, 0, stream>>>(ybuf, part);
  stats2_k<<<1, 256, 0, stream>>>(part, (const float*)d_in[20], (const float*)d_in[21], sf);
  bn_k<2><<<4096, 256, 0, stream>>>(ybuf, sf, xt, nullptr, nullptr, r2b);

  // final: out = xm + conv1x1(res)
  gemm_k<3><<<dim3(256, 2), 256, 0, stream>>>(r2b, c8p, (const float*)d_in[23], outp,
                                              nullptr, nullptr, xmct);
  aux_k<<<1, 64, 0, stream>>>(auxp, outp + 8388608);
}